// Round 4
// baseline (71.564 us; speedup 1.0000x reference)
//
#include <hip/hip_runtime.h>

// YOLO loss: N=16384, S=7, B=2, C=20. Record = 30 floats (120 B).
// R4: two cells per thread -> the 240B double-record is 16B-aligned, so all
// loads are float4. Halves strided line-visits per cell vs R1 (the measured
// bottleneck) while keeping R1's high occupancy, no divergence, no LDS tile.

constexpr float LC   = 5.0f;    // LAMBDA_COORD
constexpr float LN   = 0.5f;    // LAMBDA_NOOBJ
constexpr float EPSF = 1e-6f;

__device__ __forceinline__ float iou_pair(
    float cx1, float cy1, float w1, float h1,
    float cx2, float cy2, float w2, float h2) {
  float b1x1 = cx1 - w1 * 0.5f, b1x2 = cx1 + w1 * 0.5f;
  float b1y1 = cy1 - h1 * 0.5f, b1y2 = cy1 + h1 * 0.5f;
  float b2x1 = cx2 - w2 * 0.5f, b2x2 = cx2 + w2 * 0.5f;
  float b2y1 = cy2 - h2 * 0.5f, b2y2 = cy2 + h2 * 0.5f;
  float iw = fmaxf(fminf(b1x2, b2x2) - fmaxf(b1x1, b2x1), 0.0f);
  float ih = fmaxf(fminf(b1y2, b2y2) - fmaxf(b1y1, b2y1), 0.0f);
  float inter = iw * ih;
  float uni = w1 * h1 + w2 * h2 - inter;
  return inter / (uni + EPSF);
}

// Box/conf part of one record's loss (everything except the class SSE term).
// obj is passed in; returns obj*(LC*(xy+wh)+dc^2) + LN*noobj.
__device__ __forceinline__ float box_loss(
    float p0, float p1, float p2, float p3, float p4,
    float p5, float p6, float p7, float p8, float p9,
    float t0, float t1, float t2, float t3, float obj, float t4) {
  float iou0 = iou_pair(p0, p1, p2, p3, t0, t1, t2, t3);
  float iou1 = iou_pair(p5, p6, p7, p8, t0, t1, t2, t3);
  float v0 = iou0 > 0.0f ? iou0 : 0.0f;   // jnp.where(iou>0, iou, 0)
  float v1 = iou1 > 0.0f ? iou1 : 0.0f;
  bool pick1 = v1 > v0;                    // argmax: first index wins ties

  float bx = pick1 ? p5 : p0;
  float by = pick1 ? p6 : p1;
  float bw = pick1 ? p7 : p2;
  float bh = pick1 ? p8 : p3;
  float bc = pick1 ? p9 : p4;

  float dx = bx - t0, dy = by - t1;
  float xy = dx * dx + dy * dy;
  float sw = sqrtf(fmaxf(bw, EPSF)) - sqrtf(fmaxf(t2, EPSF));
  float sh = sqrtf(fmaxf(bh, EPSF)) - sqrtf(fmaxf(t3, EPSF));
  float wh = sw * sw + sh * sh;
  float dc = bc - t4;

  float sq0 = p4 * p4, sq1 = p9 * p9;
  float sq_all  = sq0 + sq1;
  float sq_best = pick1 ? sq1 : sq0;
  float noobj = obj * (sq_all - sq_best) + (1.0f - obj) * sq_all;

  return obj * (LC * (xy + wh) + dc * dc) + LN * noobj;
}

__device__ __forceinline__ float sqd4(float4 a, float4 b) {
  float dx = a.x - b.x, dy = a.y - b.y, dz = a.z - b.z, dw = a.w - b.w;
  return dx * dx + dy * dy + dz * dz + dw * dw;
}

__global__ __launch_bounds__(256) void yolo_pair_kernel(
    const float* __restrict__ pred, const float* __restrict__ tgt,
    float* __restrict__ partial, float invN) {
  int pair = blockIdx.x * 256 + threadIdx.x;           // 401408 pairs, exact
  const float4* p4 = (const float4*)pred + (size_t)pair * 15;
  const float4* t4 = (const float4*)tgt  + (size_t)pair * 15;

  // ---- phase 1: floats 0..31 of both streams (slots 0..7) ----
  float4 P0 = p4[0], P1 = p4[1], P2 = p4[2], P3 = p4[3];
  float4 P4_ = p4[4], P5 = p4[5], P6 = p4[6], P7 = p4[7];
  float4 T0 = t4[0], T1 = t4[1], T2 = t4[2], T3 = t4[3];
  float4 T4_ = t4[4], T5 = t4[5], T6 = t4[6], T7 = t4[7];

  // record 0: pred fields 0..9 = floats 0..9; tgt fields 0..4 = floats 0..4
  float obj0 = T1.x > 0.0f ? 1.0f : 0.0f;
  float l0 = box_loss(P0.x, P0.y, P0.z, P0.w, P1.x,
                      P1.y, P1.z, P1.w, P2.x, P2.y,
                      T0.x, T0.y, T0.z, T0.w, obj0, T1.x);
  // record 0 classes: floats 10..29
  float cls0 = (P2.z - T2.z) * (P2.z - T2.z) + (P2.w - T2.w) * (P2.w - T2.w)
             + sqd4(P3, T3) + sqd4(P4_, T4_) + sqd4(P5, T5) + sqd4(P6, T6)
             + (P7.x - T7.x) * (P7.x - T7.x) + (P7.y - T7.y) * (P7.y - T7.y);

  // ---- phase 2: floats 32..59 (slots 8..14); tgt slot 9 (fields 6..9) unused ----
  float4 Q8 = p4[8], Q9 = p4[9], Q10 = p4[10], Q11 = p4[11];
  float4 Q12 = p4[12], Q13 = p4[13], Q14 = p4[14];
  float4 U8 = t4[8];
  float4 U10 = t4[10], U11 = t4[11], U12 = t4[12], U13 = t4[13], U14 = t4[14];

  // record 1: pred fields 0..9 = floats 30..39 -> P7.z,P7.w,Q8.*,Q9.*
  //           tgt fields 0..4 = floats 30..34 -> T7.z,T7.w,U8.x,U8.y,U8.z
  float obj1 = U8.z > 0.0f ? 1.0f : 0.0f;
  float l1 = box_loss(P7.z, P7.w, Q8.x, Q8.y, Q8.z,
                      Q8.w, Q9.x, Q9.y, Q9.z, Q9.w,
                      T7.z, T7.w, U8.x, U8.y, obj1, U8.z);
  // record 1 classes: floats 40..59 -> slots 10..14 exactly
  float cls1 = sqd4(Q10, U10) + sqd4(Q11, U11) + sqd4(Q12, U12)
             + sqd4(Q13, U13) + sqd4(Q14, U14);

  float contrib = (l0 + obj0 * cls0 + l1 + obj1 * cls1) * invN;

  // wave64 shuffle reduce, then cross-wave via LDS
  for (int off = 32; off > 0; off >>= 1)
    contrib += __shfl_down(contrib, off);
  __shared__ float wsum[4];
  int lane = threadIdx.x & 63;
  int wid  = threadIdx.x >> 6;
  if (lane == 0) wsum[wid] = contrib;
  __syncthreads();
  if (threadIdx.x == 0)
    partial[blockIdx.x] = (wsum[0] + wsum[1]) + (wsum[2] + wsum[3]);
}

__global__ __launch_bounds__(256) void yolo_final_kernel(
    const float* __restrict__ partial, int n, float* __restrict__ out) {
  double s = 0.0;
  for (int i = threadIdx.x; i < n; i += 256) s += (double)partial[i];
  for (int off = 32; off > 0; off >>= 1) s += __shfl_down(s, off);
  __shared__ double wsum[4];
  int lane = threadIdx.x & 63;
  int wid  = threadIdx.x >> 6;
  if (lane == 0) wsum[wid] = s;
  __syncthreads();
  if (threadIdx.x == 0)
    out[0] = (float)((wsum[0] + wsum[1]) + (wsum[2] + wsum[3]));
}

extern "C" void kernel_launch(void* const* d_in, const int* in_sizes, int n_in,
                              void* d_out, int out_size, void* d_ws, size_t ws_size,
                              hipStream_t stream) {
  const float* pred = (const float*)d_in[0];
  const float* tgt  = (const float*)d_in[1];
  float* out = (float*)d_out;
  float* partial = (float*)d_ws;

  int ncells  = in_sizes[0] / 30;          // N*S*S = 802816 (even)
  int npairs  = ncells / 2;                // 401408
  int nblocks = npairs / 256;              // 1568 exact
  int N       = ncells / 49;               // 16384
  float invN  = 1.0f / (float)N;           // exact (power of 2)

  yolo_pair_kernel<<<nblocks, 256, 0, stream>>>(pred, tgt, partial, invN);
  yolo_final_kernel<<<1, 256, 0, stream>>>(partial, nblocks, out);
}

// Round 5
// 67.012 us; speedup vs baseline: 1.0679x; 1.0679x over previous
//
#include <hip/hip_runtime.h>

// YOLO loss: N=16384, S=7, B=2, C=20. Record = 30 floats (120 B).
// R5: split by access pattern.
//  phase 1 (gather-shaped, 1/3 of bytes): strided float2 loads of pred fields
//    0..9 and tgt fields 0..4 only -> box/conf/noobj loss + obj flag per cell.
//  phase 2 (streaming, 2/3 of bytes): fully coalesced float4 over both arrays,
//    class SSE masked by field>=10 and obj[cell] (obj via 2KB LDS lookup).
// Line-visit model: 960 + 240 = 1200 visits/128 cells vs R1's 3360.

constexpr float LC   = 5.0f;    // LAMBDA_COORD
constexpr float LN   = 0.5f;    // LAMBDA_NOOBJ
constexpr float EPSF = 1e-6f;

__device__ __forceinline__ float iou_pair(
    float cx1, float cy1, float w1, float h1,
    float cx2, float cy2, float w2, float h2) {
  float b1x1 = cx1 - w1 * 0.5f, b1x2 = cx1 + w1 * 0.5f;
  float b1y1 = cy1 - h1 * 0.5f, b1y2 = cy1 + h1 * 0.5f;
  float b2x1 = cx2 - w2 * 0.5f, b2x2 = cx2 + w2 * 0.5f;
  float b2y1 = cy2 - h2 * 0.5f, b2y2 = cy2 + h2 * 0.5f;
  float iw = fmaxf(fminf(b1x2, b2x2) - fmaxf(b1x1, b2x1), 0.0f);
  float ih = fmaxf(fminf(b1y2, b2y2) - fmaxf(b1y1, b2y1), 0.0f);
  float inter = iw * ih;
  float uni = w1 * h1 + w2 * h2 - inter;
  return inter / (uni + EPSF);
}

// Box + conf + noobj part of one cell's loss (identical math to R1, which
// validated at absmax 0). Returns the contribution; writes obj flag.
__device__ __forceinline__ float box_conf_loss(
    float p0, float p1, float p2, float p3, float p4,
    float p5, float p6, float p7, float p8, float p9,
    float t0, float t1, float t2, float t3, float t4, float& obj_out) {
  float iou0 = iou_pair(p0, p1, p2, p3, t0, t1, t2, t3);
  float iou1 = iou_pair(p5, p6, p7, p8, t0, t1, t2, t3);
  float v0 = iou0 > 0.0f ? iou0 : 0.0f;   // jnp.where(iou>0, iou, 0)
  float v1 = iou1 > 0.0f ? iou1 : 0.0f;
  bool pick1 = v1 > v0;                    // argmax: first index wins ties

  float bx = pick1 ? p5 : p0;
  float by = pick1 ? p6 : p1;
  float bw = pick1 ? p7 : p2;
  float bh = pick1 ? p8 : p3;
  float bc = pick1 ? p9 : p4;

  float obj = t4 > 0.0f ? 1.0f : 0.0f;
  obj_out = obj;

  float dx = bx - t0, dy = by - t1;
  float xy = dx * dx + dy * dy;
  float sw = sqrtf(fmaxf(bw, EPSF)) - sqrtf(fmaxf(t2, EPSF));
  float sh = sqrtf(fmaxf(bh, EPSF)) - sqrtf(fmaxf(t3, EPSF));
  float wh = sw * sw + sh * sh;
  float dc = bc - t4;

  float sq0 = p4 * p4, sq1 = p9 * p9;
  float sq_all  = sq0 + sq1;
  float sq_best = pick1 ? sq1 : sq0;
  float noobj = obj * (sq_all - sq_best) + (1.0f - obj) * sq_all;

  return obj * (LC * (xy + wh) + dc * dc) + LN * noobj;
}

__global__ __launch_bounds__(256) void yolo_fused_kernel(
    const float* __restrict__ pred, const float* __restrict__ tgt,
    float* __restrict__ partial, float invN) {
  __shared__ float sobj[4][128];   // per-wave obj flags, 2 KB total

  const int lane = threadIdx.x & 63;
  const int widx = threadIdx.x >> 6;
  const int wave = blockIdx.x * 4 + widx;   // 6272 waves, each owns 128 cells
  const int cellbase = wave * 128;

  float contrib = 0.0f;

  // ---- phase 1: strided box/conf gather (pred fields 0..9, tgt 0..4) ----
#pragma unroll
  for (int h = 0; h < 2; ++h) {
    int c = cellbase + h * 64 + lane;
    const float* p = pred + (size_t)c * 30;
    const float* t = tgt  + (size_t)c * 30;
    float2 pb0 = *(const float2*)(p + 0);
    float2 pb1 = *(const float2*)(p + 2);
    float2 pb2 = *(const float2*)(p + 4);
    float2 pb3 = *(const float2*)(p + 6);
    float2 pb4 = *(const float2*)(p + 8);
    float2 tb0 = *(const float2*)(t + 0);
    float2 tb1 = *(const float2*)(t + 2);
    float2 tb2 = *(const float2*)(t + 4);
    float obj;
    contrib += box_conf_loss(pb0.x, pb0.y, pb1.x, pb1.y, pb2.x,
                             pb2.y, pb3.x, pb3.y, pb4.x, pb4.y,
                             tb0.x, tb0.y, tb1.x, tb1.y, tb2.x, obj);
    sobj[widx][h * 64 + lane] = obj;
  }
  __syncthreads();

  // ---- phase 2: coalesced class stream (both arrays, fields 10..29) ----
  const float4* p4 = (const float4*)pred + (size_t)wave * 960;
  const float4* t4 = (const float4*)tgt  + (size_t)wave * 960;
  const float* so = sobj[widx];

  float acc = 0.0f;
#pragma unroll
  for (int j = 0; j < 15; ++j) {
    float4 P = p4[j * 64 + lane];
    float4 T = t4[j * 64 + lane];
    int gb   = j * 256 + lane * 4;     // chunk-local float index of component 0
    int c_lo = gb / 30;                // 0..127 (compiler magic-div)
    int r    = gb - c_lo * 30;         // 0..29
    float o_lo = so[c_lo];
    int c_hi = c_lo + 1; if (c_hi > 127) c_hi = 127;
    float o_hi = so[c_hi];

    float Pc[4] = {P.x, P.y, P.z, P.w};
    float Tc[4] = {T.x, T.y, T.z, T.w};
#pragma unroll
    for (int k = 0; k < 4; ++k) {
      int fld = r + k;                 // 0..32
      bool cross = fld >= 30;          // belongs to next cell, field 0..2
      bool iscls = (fld >= 10) && !cross;
      float o = cross ? o_hi : o_lo;   // (unused when cross: iscls=false)
      float d = Pc[k] - Tc[k];
      acc += (iscls ? o : 0.0f) * d * d;
    }
  }

  contrib = (contrib + acc) * invN;

  // wave64 shuffle reduce, then cross-wave via LDS
  for (int off = 32; off > 0; off >>= 1)
    contrib += __shfl_down(contrib, off);
  __shared__ float wsum[4];
  if (lane == 0) wsum[widx] = contrib;
  __syncthreads();
  if (threadIdx.x == 0)
    partial[blockIdx.x] = (wsum[0] + wsum[1]) + (wsum[2] + wsum[3]);
}

__global__ __launch_bounds__(256) void yolo_final_kernel(
    const float* __restrict__ partial, int n, float* __restrict__ out) {
  double s = 0.0;
  for (int i = threadIdx.x; i < n; i += 256) s += (double)partial[i];
  for (int off = 32; off > 0; off >>= 1) s += __shfl_down(s, off);
  __shared__ double wsum[4];
  int lane = threadIdx.x & 63;
  int wid  = threadIdx.x >> 6;
  if (lane == 0) wsum[wid] = s;
  __syncthreads();
  if (threadIdx.x == 0)
    out[0] = (float)((wsum[0] + wsum[1]) + (wsum[2] + wsum[3]));
}

extern "C" void kernel_launch(void* const* d_in, const int* in_sizes, int n_in,
                              void* d_out, int out_size, void* d_ws, size_t ws_size,
                              hipStream_t stream) {
  const float* pred = (const float*)d_in[0];
  const float* tgt  = (const float*)d_in[1];
  float* out = (float*)d_out;
  float* partial = (float*)d_ws;

  int ncells  = in_sizes[0] / 30;          // N*S*S = 802816
  int nchunks = ncells / 128;              // 6272 waves (exact)
  int nblocks = nchunks / 4;               // 1568 blocks (exact)
  int N       = ncells / 49;               // 16384
  float invN  = 1.0f / (float)N;           // exact (power of 2)

  yolo_fused_kernel<<<nblocks, 256, 0, stream>>>(pred, tgt, partial, invN);
  yolo_final_kernel<<<1, 256, 0, stream>>>(partial, nblocks, out);
}

// Round 6
// 46.472 us; speedup vs baseline: 1.5399x; 1.4420x over previous
//
#include <hip/hip_runtime.h>

// YOLO loss: N=16384, S=7, B=2, C=20. Record = 30 floats (120 B).
// R6: single-pass, 4 lanes per cell. Lane s (0..3) of cell c loads floats
// [s*8, s*8+8) of the record as float2s (8B-aligned for every cell). A wave
// covers 16 consecutive records -> each load instr spans ~15 cache lines
// (vs 60 for the 1-thread/cell strided version). Class SSE is computed
// per-lane and group-reduced via shfl; box math runs on s==0 lanes with
// pred fields 8,9 shuffled in from s==1. No LDS staging, no barriers.

constexpr float LC   = 5.0f;    // LAMBDA_COORD
constexpr float LN   = 0.5f;    // LAMBDA_NOOBJ
constexpr float EPSF = 1e-6f;

__device__ __forceinline__ float iou_pair(
    float cx1, float cy1, float w1, float h1,
    float cx2, float cy2, float w2, float h2) {
  float b1x1 = cx1 - w1 * 0.5f, b1x2 = cx1 + w1 * 0.5f;
  float b1y1 = cy1 - h1 * 0.5f, b1y2 = cy1 + h1 * 0.5f;
  float b2x1 = cx2 - w2 * 0.5f, b2x2 = cx2 + w2 * 0.5f;
  float b2y1 = cy2 - h2 * 0.5f, b2y2 = cy2 + h2 * 0.5f;
  float iw = fmaxf(fminf(b1x2, b2x2) - fmaxf(b1x1, b2x1), 0.0f);
  float ih = fmaxf(fminf(b1y2, b2y2) - fmaxf(b1y1, b2y1), 0.0f);
  float inter = iw * ih;
  float uni = w1 * h1 + w2 * h2 - inter;
  return inter / (uni + EPSF);
}

__device__ __forceinline__ float d2f2(float2 a, float2 b) {
  float dx = a.x - b.x, dy = a.y - b.y;
  return dx * dx + dy * dy;
}

__global__ __launch_bounds__(256) void yolo_quad_kernel(
    const float* __restrict__ pred, const float* __restrict__ tgt,
    float* __restrict__ partial, float invN) {
  const int tid  = threadIdx.x;
  const int lane = tid & 63;
  const int s    = lane & 3;                       // sub-lane within cell
  const int cell = (blockIdx.x * 256 + tid) >> 2;  // 4 lanes per cell

  const float* p = pred + (size_t)cell * 30 + s * 8;
  const float* t = tgt  + (size_t)cell * 30 + s * 8;

  // ---- loads: lane owns record floats [s*8, s*8+8) ----
  // pred: all needed except s==3,k==3 (would be floats 30,31)
  float2 pk0 = *(const float2*)(p + 0);
  float2 pk1 = *(const float2*)(p + 2);
  float2 pk2 = *(const float2*)(p + 4);
  float2 pk3 = make_float2(0.f, 0.f);
  if (s < 3) pk3 = *(const float2*)(p + 6);
  // tgt: s0 needs F0..5 (k0..k2); s1 needs F10..15 (k1..k3);
  //      s2 needs F16..23 (all); s3 needs F24..29 (k0..k2)
  float2 tk0 = make_float2(0.f, 0.f), tk1, tk2, tk3 = make_float2(0.f, 0.f);
  if (s != 1) tk0 = *(const float2*)(t + 0);
  tk1 = *(const float2*)(t + 2);
  tk2 = *(const float2*)(t + 4);
  if (s == 1 || s == 2) tk3 = *(const float2*)(t + 6);

  // ---- per-lane class SSE (fields 10..29) ----
  float cls = 0.0f;
  if (s == 1) {
    cls = d2f2(pk1, tk1) + d2f2(pk2, tk2) + d2f2(pk3, tk3);   // F10..15
  } else if (s == 2) {
    cls = d2f2(pk0, tk0) + d2f2(pk1, tk1) + d2f2(pk2, tk2) + d2f2(pk3, tk3); // F16..23
  } else if (s == 3) {
    cls = d2f2(pk0, tk0) + d2f2(pk1, tk1) + d2f2(pk2, tk2);   // F24..29
  }
  // group-reduce cls to s==0 lane (lanes beyond group contribute garbage to
  // other lanes' partials, but only s==0's value is consumed)
  cls += __shfl_down(cls, 1);
  cls += __shfl_down(cls, 2);

  // ---- bring pred fields 8,9 (s==1 lane's pk0) to s==0 ----
  int src1 = (lane & ~3) + 1;
  float p8 = __shfl(pk0.x, src1);
  float p9 = __shfl(pk0.y, src1);

  // ---- box/conf/noobj + total on s==0 lanes (R1-validated math) ----
  float contrib = 0.0f;
  if (s == 0) {
    float p0 = pk0.x, p1 = pk0.y, p2 = pk1.x, p3 = pk1.y, p4 = pk2.x;
    float p5 = pk2.y, p6 = pk3.x, p7 = pk3.y;
    float t0 = tk0.x, t1 = tk0.y, t2 = tk1.x, t3 = tk1.y, t4 = tk2.x;

    float iou0 = iou_pair(p0, p1, p2, p3, t0, t1, t2, t3);
    float iou1 = iou_pair(p5, p6, p7, p8, t0, t1, t2, t3);
    float v0 = iou0 > 0.0f ? iou0 : 0.0f;   // jnp.where(iou>0, iou, 0)
    float v1 = iou1 > 0.0f ? iou1 : 0.0f;
    bool pick1 = v1 > v0;                    // argmax: first index wins ties

    float bx = pick1 ? p5 : p0;
    float by = pick1 ? p6 : p1;
    float bw = pick1 ? p7 : p2;
    float bh = pick1 ? p8 : p3;
    float bc = pick1 ? p9 : p4;

    float obj = t4 > 0.0f ? 1.0f : 0.0f;

    float dx = bx - t0, dy = by - t1;
    float xy = dx * dx + dy * dy;
    float sw = sqrtf(fmaxf(bw, EPSF)) - sqrtf(fmaxf(t2, EPSF));
    float sh = sqrtf(fmaxf(bh, EPSF)) - sqrtf(fmaxf(t3, EPSF));
    float wh = sw * sw + sh * sh;
    float dc = bc - t4;

    float sq0 = p4 * p4, sq1 = p9 * p9;
    float sq_all  = sq0 + sq1;
    float sq_best = pick1 ? sq1 : sq0;
    float noobj = obj * (sq_all - sq_best) + (1.0f - obj) * sq_all;

    contrib = (obj * (LC * (xy + wh) + dc * dc + cls) + LN * noobj) * invN;
  }

  // wave64 shuffle reduce, then cross-wave via LDS
  for (int off = 32; off > 0; off >>= 1)
    contrib += __shfl_down(contrib, off);
  __shared__ float wsum[4];
  int wid = tid >> 6;
  if (lane == 0) wsum[wid] = contrib;
  __syncthreads();
  if (tid == 0)
    partial[blockIdx.x] = (wsum[0] + wsum[1]) + (wsum[2] + wsum[3]);
}

__global__ __launch_bounds__(256) void yolo_final_kernel(
    const float* __restrict__ partial, int n, float* __restrict__ out) {
  double s = 0.0;
  for (int i = threadIdx.x; i < n; i += 256) s += (double)partial[i];
  for (int off = 32; off > 0; off >>= 1) s += __shfl_down(s, off);
  __shared__ double wsum[4];
  int lane = threadIdx.x & 63;
  int wid  = threadIdx.x >> 6;
  if (lane == 0) wsum[wid] = s;
  __syncthreads();
  if (threadIdx.x == 0)
    out[0] = (float)((wsum[0] + wsum[1]) + (wsum[2] + wsum[3]));
}

extern "C" void kernel_launch(void* const* d_in, const int* in_sizes, int n_in,
                              void* d_out, int out_size, void* d_ws, size_t ws_size,
                              hipStream_t stream) {
  const float* pred = (const float*)d_in[0];
  const float* tgt  = (const float*)d_in[1];
  float* out = (float*)d_out;
  float* partial = (float*)d_ws;

  int ncells  = in_sizes[0] / 30;          // N*S*S = 802816
  int nthreads = ncells * 4;               // 4 lanes per cell
  int nblocks = nthreads / 256;            // 12544 exact
  int N       = ncells / 49;               // 16384
  float invN  = 1.0f / (float)N;           // exact (power of 2)

  yolo_quad_kernel<<<nblocks, 256, 0, stream>>>(pred, tgt, partial, invN);
  yolo_final_kernel<<<1, 256, 0, stream>>>(partial, nblocks, out);
}

// Round 7
// 39.908 us; speedup vs baseline: 1.7932x; 1.1645x over previous
//
#include <hip/hip_runtime.h>

// YOLO loss: N=16384, S=7, B=2, C=20. Record = 30 floats (120 B).
// R7: 1 thread/cell (R1 shape: low wave count, no shuffles/divergence),
// but loads as 8+8 float4 over a 32-float window starting at
// cell*30 - 2*(cell&1)  -> byte base 120c (even) / 120c-8 (odd), both
// 16B-aligned. Field i = window[i + 2*odd] via compile-time-indexed selects.
// Class SSE = full-window d2 sum minus non-class window elements.
// Cuts strided line-visits 28 instr -> 16 instr (x60 lines each).

constexpr float LC   = 5.0f;    // LAMBDA_COORD
constexpr float LN   = 0.5f;    // LAMBDA_NOOBJ
constexpr float EPSF = 1e-6f;

__device__ __forceinline__ float iou_pair(
    float cx1, float cy1, float w1, float h1,
    float cx2, float cy2, float w2, float h2) {
  float b1x1 = cx1 - w1 * 0.5f, b1x2 = cx1 + w1 * 0.5f;
  float b1y1 = cy1 - h1 * 0.5f, b1y2 = cy1 + h1 * 0.5f;
  float b2x1 = cx2 - w2 * 0.5f, b2x2 = cx2 + w2 * 0.5f;
  float b2y1 = cy2 - h2 * 0.5f, b2y2 = cy2 + h2 * 0.5f;
  float iw = fmaxf(fminf(b1x2, b2x2) - fmaxf(b1x1, b2x1), 0.0f);
  float ih = fmaxf(fminf(b1y2, b2y2) - fmaxf(b1y1, b2y1), 0.0f);
  float inter = iw * ih;
  float uni = w1 * h1 + w2 * h2 - inter;
  return inter / (uni + EPSF);
}

__global__ __launch_bounds__(256) void yolo_win_kernel(
    const float* __restrict__ pred, const float* __restrict__ tgt,
    float* __restrict__ partial, float invN) {
  const int tid  = threadIdx.x;
  const int cell = blockIdx.x * 256 + tid;
  const int odd  = cell & 1;

  // 16B-aligned 32-float window covering the whole record (+2 edge floats).
  const size_t wbase = (size_t)cell * 30 - 2 * odd;
  const float4* p4 = (const float4*)(pred + wbase);
  const float4* t4 = (const float4*)(tgt + wbase);

  // Issue all 16 loads up front (independent -> deep MLP).
  float4 P0 = p4[0], P1 = p4[1], P2 = p4[2], P3 = p4[3];
  float4 P4_ = p4[4], P5 = p4[5], P6 = p4[6], P7 = p4[7];
  float4 T0 = t4[0], T1 = t4[1], T2 = t4[2], T3 = t4[3];
  float4 T4_ = t4[4], T5 = t4[5], T6 = t4[6], T7 = t4[7];

  // Flatten to compile-time-indexed arrays (stays in registers).
  float wp[32] = {P0.x,P0.y,P0.z,P0.w, P1.x,P1.y,P1.z,P1.w,
                  P2.x,P2.y,P2.z,P2.w, P3.x,P3.y,P3.z,P3.w,
                  P4_.x,P4_.y,P4_.z,P4_.w, P5.x,P5.y,P5.z,P5.w,
                  P6.x,P6.y,P6.z,P6.w, P7.x,P7.y,P7.z,P7.w};
  float wt[32] = {T0.x,T0.y,T0.z,T0.w, T1.x,T1.y,T1.z,T1.w,
                  T2.x,T2.y,T2.z,T2.w, T3.x,T3.y,T3.z,T3.w,
                  T4_.x,T4_.y,T4_.z,T4_.w, T5.x,T5.y,T5.z,T5.w,
                  T6.x,T6.y,T6.z,T6.w, T7.x,T7.y,T7.z,T7.w};

  // Per-element squared diffs (all compile-time indices).
  float d2[32];
#pragma unroll
  for (int k = 0; k < 32; ++k) {
    float d = wp[k] - wt[k];
    d2[k] = d * d;
  }

  // total window SSE (tree-ish sum)
  float s0 = (d2[0]+d2[1]) + (d2[2]+d2[3]);
  float s1 = (d2[4]+d2[5]) + (d2[6]+d2[7]);
  float s2 = (d2[8]+d2[9]) + (d2[10]+d2[11]);
  float s3 = (d2[12]+d2[13]) + (d2[14]+d2[15]);
  float s4 = (d2[16]+d2[17]) + (d2[18]+d2[19]);
  float s5 = (d2[20]+d2[21]) + (d2[22]+d2[23]);
  float s6 = (d2[24]+d2[25]) + (d2[26]+d2[27]);
  float s7 = (d2[28]+d2[29]) + (d2[30]+d2[31]);
  float total32 = ((s0+s1)+(s2+s3)) + ((s4+s5)+(s6+s7));

  // non-class subtraction: fields 0..9 (window 0..9 or 2..11) plus edges.
  float common = ((d2[0]+d2[1]) + (d2[2]+d2[3])) +
                 ((d2[4]+d2[5]) + (d2[6]+d2[7])) + (d2[8]+d2[9]);
  float extra  = odd ? (d2[10] + d2[11]) : (d2[30] + d2[31]);
  float cls = total32 - common - extra;

  // record fields: field i = w[i + 2*odd]  (15 cndmask selects)
  float p0 = odd ? wp[2]  : wp[0];
  float p1 = odd ? wp[3]  : wp[1];
  float p2 = odd ? wp[4]  : wp[2];
  float p3 = odd ? wp[5]  : wp[3];
  float p4v= odd ? wp[6]  : wp[4];
  float p5 = odd ? wp[7]  : wp[5];
  float p6 = odd ? wp[8]  : wp[6];
  float p7 = odd ? wp[9]  : wp[7];
  float p8 = odd ? wp[10] : wp[8];
  float p9 = odd ? wp[11] : wp[9];
  float t0 = odd ? wt[2]  : wt[0];
  float t1 = odd ? wt[3]  : wt[1];
  float t2 = odd ? wt[4]  : wt[2];
  float t3 = odd ? wt[5]  : wt[3];
  float t4v= odd ? wt[6]  : wt[4];

  // ---- box/conf/noobj (R1-validated math) ----
  float iou0 = iou_pair(p0, p1, p2, p3, t0, t1, t2, t3);
  float iou1 = iou_pair(p5, p6, p7, p8, t0, t1, t2, t3);
  float v0 = iou0 > 0.0f ? iou0 : 0.0f;   // jnp.where(iou>0, iou, 0)
  float v1 = iou1 > 0.0f ? iou1 : 0.0f;
  bool pick1 = v1 > v0;                    // argmax: first index wins ties

  float bx = pick1 ? p5 : p0;
  float by = pick1 ? p6 : p1;
  float bw = pick1 ? p7 : p2;
  float bh = pick1 ? p8 : p3;
  float bc = pick1 ? p9 : p4v;

  float obj = t4v > 0.0f ? 1.0f : 0.0f;

  float dx = bx - t0, dy = by - t1;
  float xy = dx * dx + dy * dy;
  float sw = sqrtf(fmaxf(bw, EPSF)) - sqrtf(fmaxf(t2, EPSF));
  float sh = sqrtf(fmaxf(bh, EPSF)) - sqrtf(fmaxf(t3, EPSF));
  float wh = sw * sw + sh * sh;
  float dc = bc - t4v;

  float sq0 = p4v * p4v, sq1 = p9 * p9;
  float sq_all  = sq0 + sq1;
  float sq_best = pick1 ? sq1 : sq0;
  float noobj = obj * (sq_all - sq_best) + (1.0f - obj) * sq_all;

  float contrib = (obj * (LC * (xy + wh) + dc * dc + cls) + LN * noobj) * invN;

  // wave64 shuffle reduce, then cross-wave via LDS
  for (int off = 32; off > 0; off >>= 1)
    contrib += __shfl_down(contrib, off);
  __shared__ float wsum[4];
  int lane = tid & 63;
  int wid  = tid >> 6;
  if (lane == 0) wsum[wid] = contrib;
  __syncthreads();
  if (tid == 0)
    partial[blockIdx.x] = (wsum[0] + wsum[1]) + (wsum[2] + wsum[3]);
}

__global__ __launch_bounds__(256) void yolo_final_kernel(
    const float* __restrict__ partial, int n, float* __restrict__ out) {
  double s = 0.0;
  for (int i = threadIdx.x; i < n; i += 256) s += (double)partial[i];
  for (int off = 32; off > 0; off >>= 1) s += __shfl_down(s, off);
  __shared__ double wsum[4];
  int lane = threadIdx.x & 63;
  int wid  = threadIdx.x >> 6;
  if (lane == 0) wsum[wid] = s;
  __syncthreads();
  if (threadIdx.x == 0)
    out[0] = (float)((wsum[0] + wsum[1]) + (wsum[2] + wsum[3]));
}

extern "C" void kernel_launch(void* const* d_in, const int* in_sizes, int n_in,
                              void* d_out, int out_size, void* d_ws, size_t ws_size,
                              hipStream_t stream) {
  const float* pred = (const float*)d_in[0];
  const float* tgt  = (const float*)d_in[1];
  float* out = (float*)d_out;
  float* partial = (float*)d_ws;

  int ncells  = in_sizes[0] / 30;          // N*S*S = 802816
  int nblocks = ncells / 256;              // 3136 exact
  int N       = ncells / 49;               // 16384
  float invN  = 1.0f / (float)N;           // exact (power of 2)

  yolo_win_kernel<<<nblocks, 256, 0, stream>>>(pred, tgt, partial, invN);
  yolo_final_kernel<<<1, 256, 0, stream>>>(partial, nblocks, out);
}

// Round 8
// 39.657 us; speedup vs baseline: 1.8046x; 1.0063x over previous
//
#include <hip/hip_runtime.h>

// YOLO loss: N=16384, S=7, B=2, C=20. Record = 30 floats (120 B).
// R8: 2 lanes per cell. Cell c's 32-float window starts at 30c-2*(c&1)
// (16B-aligned byte base for both parities). Lane s in {0,1} loads window
// floats [16s,16s+16) of both arrays as 4+4 float4. A wave-load's 64 lane
// addresses tile a contiguous ~3.8KB footprint (30 lines) -> near-coalesced.
// Box/conf math runs entirely on s==0 lanes (fields 0..9 pred / 0..4 tgt all
// live in window 0..15 for both parities); class SSE is computed per-lane
// with compile-time masks and combined with ONE shfl_down. Single pass,
// no LDS staging, no barriers.

constexpr float LC   = 5.0f;    // LAMBDA_COORD
constexpr float LN   = 0.5f;    // LAMBDA_NOOBJ
constexpr float EPSF = 1e-6f;

__device__ __forceinline__ float iou_pair(
    float cx1, float cy1, float w1, float h1,
    float cx2, float cy2, float w2, float h2) {
  float b1x1 = cx1 - w1 * 0.5f, b1x2 = cx1 + w1 * 0.5f;
  float b1y1 = cy1 - h1 * 0.5f, b1y2 = cy1 + h1 * 0.5f;
  float b2x1 = cx2 - w2 * 0.5f, b2x2 = cx2 + w2 * 0.5f;
  float b2y1 = cy2 - h2 * 0.5f, b2y2 = cy2 + h2 * 0.5f;
  float iw = fmaxf(fminf(b1x2, b2x2) - fmaxf(b1x1, b2x1), 0.0f);
  float ih = fmaxf(fminf(b1y2, b2y2) - fmaxf(b1y1, b2y1), 0.0f);
  float inter = iw * ih;
  float uni = w1 * h1 + w2 * h2 - inter;
  return inter / (uni + EPSF);
}

__global__ __launch_bounds__(256) void yolo_duo_kernel(
    const float* __restrict__ pred, const float* __restrict__ tgt,
    float* __restrict__ partial, float invN) {
  const int tid  = threadIdx.x;
  const int gid  = blockIdx.x * 256 + tid;
  const int s    = gid & 1;            // sub-lane: 0 = low half+box, 1 = high half
  const int cell = gid >> 1;           // 2 lanes per cell
  const int odd  = cell & 1;

  // 16B-aligned 32-float window covering the record (+2 edge floats for odd).
  const size_t wbase = (size_t)cell * 30 - 2 * odd;
  const float4* p4 = (const float4*)(pred + wbase) + 4 * s;
  const float4* t4 = (const float4*)(tgt + wbase) + 4 * s;

  float4 P0 = p4[0], P1 = p4[1], P2 = p4[2], P3 = p4[3];
  float4 T0 = t4[0], T1 = t4[1], T2 = t4[2], T3 = t4[3];

  float wp[16] = {P0.x,P0.y,P0.z,P0.w, P1.x,P1.y,P1.z,P1.w,
                  P2.x,P2.y,P2.z,P2.w, P3.x,P3.y,P3.z,P3.w};
  float wt[16] = {T0.x,T0.y,T0.z,T0.w, T1.x,T1.y,T1.z,T1.w,
                  T2.x,T2.y,T2.z,T2.w, T3.x,T3.y,T3.z,T3.w};

  float d2[16];
#pragma unroll
  for (int k = 0; k < 16; ++k) {
    float d = wp[k] - wt[k];
    d2[k] = d * d;
  }

  // ---- per-lane class partial ----
  // s==0 owns window 10..15: even -> fields 10..15 (all class);
  //                          odd  -> fields  8..13, class = window 12..15.
  // s==1 owns window 16..31 (local 0..15): even -> fields 16..31, exclude
  //   local 14,15 (fields 30,31 = next record); odd -> fields 14..29 (all).
  float cls_part;
  {
    float hi6 = ((d2[10] + d2[11]) + (d2[12] + d2[13])) + (d2[14] + d2[15]);
    float cls0 = odd ? (hi6 - d2[10] - d2[11]) : hi6;
    float s0 = (d2[0] + d2[1]) + (d2[2] + d2[3]);
    float s1 = (d2[4] + d2[5]) + (d2[6] + d2[7]);
    float s2 = (d2[8] + d2[9]) + (d2[10] + d2[11]);
    float s3 = (d2[12] + d2[13]) + (d2[14] + d2[15]);
    float all16 = (s0 + s1) + (s2 + s3);
    float cls1 = odd ? all16 : (all16 - d2[14] - d2[15]);
    cls_part = s ? cls1 : cls0;
  }
  // combine pair: s==0 lane receives s==1 lane's partial (adjacent lane).
  float cls = cls_part + __shfl_down(cls_part, 1);

  // ---- box/conf/noobj on s==0 lanes (fields f at window f+2*odd <= 11) ----
  float contrib = 0.0f;
  if (s == 0) {
    float p0 = odd ? wp[2]  : wp[0];
    float p1 = odd ? wp[3]  : wp[1];
    float p2 = odd ? wp[4]  : wp[2];
    float p3 = odd ? wp[5]  : wp[3];
    float p4v= odd ? wp[6]  : wp[4];
    float p5 = odd ? wp[7]  : wp[5];
    float p6 = odd ? wp[8]  : wp[6];
    float p7 = odd ? wp[9]  : wp[7];
    float p8 = odd ? wp[10] : wp[8];
    float p9 = odd ? wp[11] : wp[9];
    float t0 = odd ? wt[2]  : wt[0];
    float t1 = odd ? wt[3]  : wt[1];
    float t2 = odd ? wt[4]  : wt[2];
    float t3 = odd ? wt[5]  : wt[3];
    float t4v= odd ? wt[6]  : wt[4];

    float iou0 = iou_pair(p0, p1, p2, p3, t0, t1, t2, t3);
    float iou1 = iou_pair(p5, p6, p7, p8, t0, t1, t2, t3);
    float v0 = iou0 > 0.0f ? iou0 : 0.0f;   // jnp.where(iou>0, iou, 0)
    float v1 = iou1 > 0.0f ? iou1 : 0.0f;
    bool pick1 = v1 > v0;                    // argmax: first index wins ties

    float bx = pick1 ? p5 : p0;
    float by = pick1 ? p6 : p1;
    float bw = pick1 ? p7 : p2;
    float bh = pick1 ? p8 : p3;
    float bc = pick1 ? p9 : p4v;

    float obj = t4v > 0.0f ? 1.0f : 0.0f;

    float dx = bx - t0, dy = by - t1;
    float xy = dx * dx + dy * dy;
    float sw = sqrtf(fmaxf(bw, EPSF)) - sqrtf(fmaxf(t2, EPSF));
    float sh = sqrtf(fmaxf(bh, EPSF)) - sqrtf(fmaxf(t3, EPSF));
    float wh = sw * sw + sh * sh;
    float dc = bc - t4v;

    float sq0 = p4v * p4v, sq1 = p9 * p9;
    float sq_all  = sq0 + sq1;
    float sq_best = pick1 ? sq1 : sq0;
    float noobj = obj * (sq_all - sq_best) + (1.0f - obj) * sq_all;

    contrib = (obj * (LC * (xy + wh) + dc * dc + cls) + LN * noobj) * invN;
  }

  // wave64 shuffle reduce, then cross-wave via LDS
  for (int off = 32; off > 0; off >>= 1)
    contrib += __shfl_down(contrib, off);
  __shared__ float wsum[4];
  int lane = tid & 63;
  int wid  = tid >> 6;
  if (lane == 0) wsum[wid] = contrib;
  __syncthreads();
  if (tid == 0)
    partial[blockIdx.x] = (wsum[0] + wsum[1]) + (wsum[2] + wsum[3]);
}

__global__ __launch_bounds__(256) void yolo_final_kernel(
    const float* __restrict__ partial, int n, float* __restrict__ out) {
  double s = 0.0;
  for (int i = threadIdx.x; i < n; i += 256) s += (double)partial[i];
  for (int off = 32; off > 0; off >>= 1) s += __shfl_down(s, off);
  __shared__ double wsum[4];
  int lane = threadIdx.x & 63;
  int wid  = threadIdx.x >> 6;
  if (lane == 0) wsum[wid] = s;
  __syncthreads();
  if (threadIdx.x == 0)
    out[0] = (float)((wsum[0] + wsum[1]) + (wsum[2] + wsum[3]));
}

extern "C" void kernel_launch(void* const* d_in, const int* in_sizes, int n_in,
                              void* d_out, int out_size, void* d_ws, size_t ws_size,
                              hipStream_t stream) {
  const float* pred = (const float*)d_in[0];
  const float* tgt  = (const float*)d_in[1];
  float* out = (float*)d_out;
  float* partial = (float*)d_ws;

  int ncells  = in_sizes[0] / 30;          // N*S*S = 802816
  int nblocks = ncells * 2 / 256;          // 6272 exact (2 lanes/cell)
  int N       = ncells / 49;               // 16384
  float invN  = 1.0f / (float)N;           // exact (power of 2)

  yolo_duo_kernel<<<nblocks, 256, 0, stream>>>(pred, tgt, partial, invN);
  yolo_final_kernel<<<1, 256, 0, stream>>>(partial, nblocks, out);
}